// Round 2
// baseline (302.420 us; speedup 1.0000x reference)
//
#include <hip/hip_runtime.h>
#include <hip/hip_fp16.h>

typedef unsigned int uint;
typedef _Float16 h2 __attribute__((ext_vector_type(2)));

// Fused per-sample dynamic conv network.
// x: (8,3,1024,1024) f32, thumb: (8,3,256,256) f32, feature: (8,492) f32
// out = [x_out flat, thumb flat], f32.
//
// 64x32 tile, UNIFORM conv geometry: every layer computes rows 1..40,
// px 2..73 (360 threads = 20 row-pairs x 18 strips). Garbage creeps inward
// 1 px/layer from the fixed border exactly as the needed set shrinks
// (borderline-exact on all 4 sides). Uniform geometry => per-thread LDS
// base computed once, all conv reads/writes are base+imm offsets, and
// bu=2c is even so each 4-dword row read is 2x 8B LDS reads.
// Row stride W_U=42 (=10 mod 32) spreads row-groups across banks.
// Conv math in packed fp16 (v_pk_fma_f16), identical op order to r1.
// Epilogue (conv1x1 + residual + attention poly) fp32, 2 rows/thread.

#define ROWS   42
#define W_U    42            // LDS row stride (dwords)
#define W_REAL 38            // staged dwords (76 px) per row
#define CHP_U  (ROWS*W_U)    // 1764 dwords per channel
#define BUF_U  (3*CHP_U)     // 5292 dwords per buffer

__device__ __forceinline__ h2   U2H(uint u) { return __builtin_bit_cast(h2, u); }
__device__ __forceinline__ uint H2U(h2 h)   { return __builtin_bit_cast(uint, h); }

// ---------------- prep: pack per-sample conv3 weights as {w,w} half2 ----------------
// table layout per sample (stride 448 dwords):
//   [0..404]   conv3 weights, idx = l*81 + ic*27 + ky*9 + oc*3 + kx
//   [405..419] conv3 bias,    idx = 405 + l*3 + oc
__global__ void prep_weights(const float* __restrict__ feat, uint* __restrict__ wtab)
{
    const int b = blockIdx.x;
    const int t = threadIdx.x;
    float w = 0.f;
    bool valid = false;
    if (t < 405) {
        int l = t / 81, r = t % 81;
        int ic = r / 27; r %= 27;
        int ky = r / 9;  r %= 9;
        int oc = r / 3;
        int kx = r % 3;
        w = feat[b * 492 + l * 84 + ((oc * 3 + ic) * 3 + ky) * 3 + kx];
        valid = true;
    } else if (t < 420) {
        int i = t - 405;
        w = feat[b * 492 + (i / 3) * 84 + 81 + (i % 3)];
        valid = true;
    }
    if (valid) {
        _Float16 h = (_Float16)w;
        h2 hh = { h, h };
        wtab[b * 448 + t] = H2U(hh);
    }
}

// ---------------- main fused kernel ----------------
__global__ __launch_bounds__(512, 6) void fused_net(
    const float* __restrict__ xin,
    const float* __restrict__ thumb,
    const float* __restrict__ feat,
    const uint*  __restrict__ wtab,
    float* __restrict__ out)
{
    const int tid = threadIdx.x;

    // ---- thumb passthrough blocks (whole block exits before any barrier) ----
    if (blockIdx.x == 16) {
        const int part = blockIdx.y + 32 * blockIdx.z;     // 0..255
        const float4* s4 = (const float4*)thumb;
        float4* d4 = (float4*)(out + 25165824ull);
        const int n4 = 1572864 / 4;
        for (int i = part * 512 + tid; i < n4; i += 256 * 512)
            d4[i] = s4[i];
        return;
    }

    const int gx0 = blockIdx.x * 64;
    const int gy0 = blockIdx.y * 32;
    const int b   = blockIdx.z;
    const bool edge = (gx0 == 0) | (gx0 == 960) | (gy0 == 0) | (gy0 == 992);
    const float* wf = feat + b * 492;        // uniform fp32 (epilogue)
    const uint*  wt = wtab + b * 448;        // uniform packed half2 (conv)

    __shared__ __align__(16) uint lds[2 * BUF_U + 8];
    uint* b0 = lds;
    uint* b1 = lds + BUF_U + 4;              // dword offset 5296 -> 16B aligned

    // ---- stage: f32 global -> half2 LDS. dword u <-> gx = gx0-6+2u (even) ----
    const float* xb = xin + ((size_t)(b * 3) << 20);
    if (!edge) {
        for (int idx = tid; idx < 3 * ROWS * W_REAL; idx += 512) {
            int ch  = idx / (ROWS * W_REAL);
            int rem = idx - ch * (ROWS * W_REAL);
            int row = rem / W_REAL;
            int u   = rem - row * W_REAL;
            const float2 f = *(const float2*)(xb + ((size_t)ch << 20) +
                                              ((size_t)(gy0 - 5 + row) << 10) +
                                              (gx0 - 6 + 2 * u));
            b0[ch * CHP_U + row * W_U + u] =
                __builtin_bit_cast(uint, __builtin_amdgcn_cvt_pkrtz(f.x, f.y));
        }
    } else {
        for (int idx = tid; idx < 3 * ROWS * W_REAL; idx += 512) {
            int ch  = idx / (ROWS * W_REAL);
            int rem = idx - ch * (ROWS * W_REAL);
            int row = rem / W_REAL;
            int u   = rem - row * W_REAL;
            const int gy = gy0 - 5 + row;
            const int gx = gx0 - 6 + 2 * u;   // even; gx<1024 => gx+1<=1023
            float2 f = {0.f, 0.f};
            if ((unsigned)gy < 1024u && (unsigned)gx < 1024u)
                f = *(const float2*)(xb + ((size_t)ch << 20) + ((size_t)gy << 10) + gx);
            b0[ch * CHP_U + row * W_U + u] =
                __builtin_bit_cast(uint, __builtin_amdgcn_cvt_pkrtz(f.x, f.y));
        }
    }
    __syncthreads();

    // ---- epilogue coords + pre-read residual (b0 is clobbered at l=1) ----
    const int er  = tid >> 5;                // 0..15
    const int uc  = tid & 31;                // out dword 3+uc (px 6..69)
    const int ub0 = (5 + er) * W_U + 3 + uc;
    const int ub1 = ub0 + 16 * W_U;
    uint resu[2][3];
    #pragma unroll
    for (int ch = 0; ch < 3; ++ch) {
        resu[0][ch] = b0[ch * CHP_U + ub0];
        resu[1][ch] = b0[ch * CHP_U + ub1];
    }

    // ---- conv thread coords (uniform across layers) + hoisted border masks ----
    const int cr = tid / 18;                 // 0..19  (valid when tid<360)
    const int cc = tid - cr * 18;            // 0..17
    const int y0 = 1 + 2 * cr;               // rows y0,y0+1 in 1..40
    const int x0 = 2 + 4 * cc;               // px x0..x0+3 in 2..73
    uint mA[2] = {~0u, ~0u}, mB[2] = {~0u, ~0u};
    if (edge) {
        const int gyA = gy0 - 5 + y0;
        const int gxA = gx0 - 6 + x0;
        const uint mA0 = ((((unsigned)gxA       < 1024u) ? 0x0000ffffu : 0u) |
                          (((unsigned)(gxA + 1) < 1024u) ? 0xffff0000u : 0u));
        const uint mB0 = ((((unsigned)(gxA + 2) < 1024u) ? 0x0000ffffu : 0u) |
                          (((unsigned)(gxA + 3) < 1024u) ? 0xffff0000u : 0u));
        #pragma unroll
        for (int j = 0; j < 2; ++j) {
            const uint mr = ((unsigned)(gyA + j) < 1024u) ? ~0u : 0u;
            mA[j] = mA0 & mr;
            mB[j] = mB0 & mr;
        }
    }

    const h2 c02 = { (_Float16)0.2f, (_Float16)0.2f };

    // ---- 5 conv3x3 residual+leaky layers, packed fp16, ping-pong ----
    // Thread = 4px x 2 rows; input rows streamed (row t feeds out row j via
    // ky=t-j); center residual folded at t=1/t=2. All LDS addrs base+imm.
    #pragma unroll
    for (int l = 0; l < 5; ++l) {
        const uint* sb = (l & 1) ? b1 : b0;
        uint*       db = (l & 1) ? b0 : b1;
        if (tid < 360) {
            const uint* tb = sb + (y0 - 1) * W_U + 2 * cc;   // even dword -> 8B reads
            uint*       ob = db + y0 * W_U + 1 + 2 * cc;
            h2 accA[2][3], accB[2][3];
            #pragma unroll
            for (int oc = 0; oc < 3; ++oc) {
                const h2 bi = U2H(wt[405 + l * 3 + oc]);
                accA[0][oc] = bi; accA[1][oc] = bi;
                accB[0][oc] = bi; accB[1][oc] = bi;
            }
            #pragma unroll
            for (int ic = 0; ic < 3; ++ic) {
                #pragma unroll
                for (int t = 0; t < 4; ++t) {
                    const uint2 P = *(const uint2*)(tb + ic * CHP_U + t * W_U);
                    const uint2 Q = *(const uint2*)(tb + ic * CHP_U + t * W_U + 2);
                    const uint u0 = P.x, u1 = P.y, u2 = Q.x, u3 = Q.y;
                    const h2 X01 = U2H((u0 >> 16) | (u1 << 16));   // halves {1,2}
                    const h2 C1  = U2H(u1);
                    const h2 X12 = U2H((u1 >> 16) | (u2 << 16));   // halves {3,4}
                    const h2 C2  = U2H(u2);
                    const h2 X23 = U2H((u2 >> 16) | (u3 << 16));   // halves {5,6}
                    #pragma unroll
                    for (int j = 0; j < 2; ++j) {
                        const int ky = t - j;
                        if (0 <= ky && ky <= 2) {
                            const int wb = l * 81 + (ic * 3 + ky) * 9;
                            #pragma unroll
                            for (int oc = 0; oc < 3; ++oc) {
                                const h2 w0 = U2H(wt[wb + oc * 3 + 0]);
                                const h2 w1 = U2H(wt[wb + oc * 3 + 1]);
                                const h2 w2 = U2H(wt[wb + oc * 3 + 2]);
                                accA[j][oc] = __builtin_elementwise_fma(w0, X01, accA[j][oc]);
                                accA[j][oc] = __builtin_elementwise_fma(w1, C1,  accA[j][oc]);
                                accA[j][oc] = __builtin_elementwise_fma(w2, X12, accA[j][oc]);
                                accB[j][oc] = __builtin_elementwise_fma(w0, X12, accB[j][oc]);
                                accB[j][oc] = __builtin_elementwise_fma(w1, C2,  accB[j][oc]);
                                accB[j][oc] = __builtin_elementwise_fma(w2, X23, accB[j][oc]);
                            }
                        }
                    }
                    if (t == 1) { accA[0][ic] = accA[0][ic] + C1; accB[0][ic] = accB[0][ic] + C2; }
                    if (t == 2) { accA[1][ic] = accA[1][ic] + C1; accB[1][ic] = accB[1][ic] + C2; }
                }
            }
            // leaky 0.2 = max(v, 0.2*v); mask = ~0 for interior blocks
            #pragma unroll
            for (int j = 0; j < 2; ++j) {
                #pragma unroll
                for (int oc = 0; oc < 3; ++oc) {
                    h2 vA = accA[j][oc]; vA = __builtin_elementwise_max(vA, c02 * vA);
                    h2 vB = accB[j][oc]; vB = __builtin_elementwise_max(vB, c02 * vB);
                    ob[oc * CHP_U + j * W_U]     = H2U(vA) & mA[j];
                    ob[oc * CHP_U + j * W_U + 1] = H2U(vB) & mB[j];
                }
            }
        }
        __syncthreads();
    }
    // final conv3 result is in b1

    // ---- epilogue: conv1x1 + global residual + attention (fp32), 2 rows ----
    float* outb = out + ((size_t)(b * 3) << 20);
    #pragma unroll
    for (int rr = 0; rr < 2; ++rr) {
        const int ub = rr ? ub1 : ub0;
        const int gy = gy0 + er + 16 * rr;
        float x5f[3][2], resf[3][2];
        #pragma unroll
        for (int ch = 0; ch < 3; ++ch) {
            h2 hr = U2H(resu[rr][ch]);
            resf[ch][0] = (float)hr.x; resf[ch][1] = (float)hr.y;
            h2 hx = U2H(b1[ch * CHP_U + ub]);
            x5f[ch][0] = (float)hx.x; x5f[ch][1] = (float)hx.y;
        }
        const float h1 = (float)gy * (1.0f / 1024.0f);
        const float h2v = h1 * h1, h3 = h2v * h1;
        float tmp[3][2];
        #pragma unroll
        for (int j = 0; j < 2; ++j) {
            const float wc = (float)(gx0 + 2 * uc + j) * (1.0f / 1024.0f);
            const float w2 = wc * wc, w3 = w2 * wc;
            const float hw = h1 * wc, h2w = h2v * wc, hw2 = h1 * w2;
            #pragma unroll
            for (int oc = 0; oc < 3; ++oc) {
                float s = x5f[oc][j] + wf[429 + oc]
                        + wf[420 + oc * 3 + 0] * x5f[0][j]
                        + wf[420 + oc * 3 + 1] * x5f[1][j]
                        + wf[420 + oc * 3 + 2] * x5f[2][j];
                s = s >= 0.f ? s : 0.2f * s;
                const float xf = resf[oc][j] + s;
                const float x1 = xf, x2 = x1 * x1, x3 = x2 * x1;
                const float* cf = wf + 432 + oc * 20;
                float att =
                    cf[0] * h3 + cf[1] * h2w + cf[2] * h2v * x1 + cf[3] * h2v +
                    cf[4] * hw2 + cf[5] * hw * x1 + cf[6] * hw + cf[7] * h1 * x2 +
                    cf[8] * h1 * x1 + cf[9] * h1 + cf[10] * w3 + cf[11] * w2 * x1 +
                    cf[12] * w2 + cf[13] * wc * x2 + cf[14] * wc * x1 + cf[15] * wc +
                    cf[16] * x3 + cf[17] * x2 + cf[18] * x1 + cf[19];
                tmp[oc][j] = xf * (1.f + att);
            }
        }
        #pragma unroll
        for (int oc = 0; oc < 3; ++oc) {
            float2 v = {tmp[oc][0], tmp[oc][1]};
            *(float2*)&outb[((size_t)oc << 20) + ((size_t)gy << 10) + (gx0 + 2 * uc)] = v;
        }
    }
}

extern "C" void kernel_launch(void* const* d_in, const int* in_sizes, int n_in,
                              void* d_out, int out_size, void* d_ws, size_t ws_size,
                              hipStream_t stream) {
    const float* x     = (const float*)d_in[0];
    const float* thumb = (const float*)d_in[1];
    const float* feat  = (const float*)d_in[2];
    float* out = (float*)d_out;
    uint* wtab = (uint*)d_ws;   // 8 * 448 dwords = 14336 B

    prep_weights<<<dim3(8), 448, 0, stream>>>(feat, wtab);
    dim3 grid(17, 32, 8);       // x==16 blocks do the thumb copy
    fused_net<<<grid, 512, 0, stream>>>(x, thumb, feat, wtab, out);
}

// Round 3
// 288.412 us; speedup vs baseline: 1.0486x; 1.0486x over previous
//
#include <hip/hip_runtime.h>
#include <hip/hip_fp16.h>

typedef unsigned int uint;
typedef _Float16 h2 __attribute__((ext_vector_type(2)));

// Fused per-sample dynamic conv network.
// x: (8,3,1024,1024) f32, thumb: (8,3,256,256) f32, feature: (8,492) f32
// out = [x_out flat, thumb flat], f32.
//
// 64x32 tile, UNIFORM conv geometry: every layer computes rows 1..40,
// local px 2..73 (360 threads = 20 row-pairs x 18 strips). Garbage creeps
// inward 1 px/layer from the fixed border exactly as the needed set
// shrinks. Per-thread LDS base computed once; all conv reads/writes are
// base+imm offsets; reads are even-dword 8B ds_reads.
// W_U=40 (was 42): LDS 40448B -> 4 blocks/CU = 32 waves (occupancy max;
// r2's 42.5KB gave only 3 blocks/CU = the round-2 flat result).
// Row-to-row bank shift 16, 4-rows-apart aliasing is 2-way = free.
// Store masks only on edge blocks (uniform branch); stage loop uses
// incremental carry indexing (no per-iter div/mod).
// Conv math packed fp16 (v_pk_fma_f16); epilogue fp32.

#define ROWS   42
#define W_U    40            // LDS row stride (dwords): 38 real + 2 pad
#define W_REAL 38            // staged dwords (76 px) per row
#define CHP_U  (ROWS*W_U)    // 1680 dwords per channel
#define BUF_U  (3*CHP_U)     // 5040 dwords per buffer

__device__ __forceinline__ h2   U2H(uint u) { return __builtin_bit_cast(h2, u); }
__device__ __forceinline__ uint H2U(h2 h)   { return __builtin_bit_cast(uint, h); }

// ---------------- prep: pack per-sample conv3 weights as {w,w} half2 ----------------
// table layout per sample (stride 448 dwords):
//   [0..404]   conv3 weights, idx = l*81 + ic*27 + ky*9 + oc*3 + kx
//   [405..419] conv3 bias,    idx = 405 + l*3 + oc
__global__ void prep_weights(const float* __restrict__ feat, uint* __restrict__ wtab)
{
    const int b = blockIdx.x;
    const int t = threadIdx.x;
    float w = 0.f;
    bool valid = false;
    if (t < 405) {
        int l = t / 81, r = t % 81;
        int ic = r / 27; r %= 27;
        int ky = r / 9;  r %= 9;
        int oc = r / 3;
        int kx = r % 3;
        w = feat[b * 492 + l * 84 + ((oc * 3 + ic) * 3 + ky) * 3 + kx];
        valid = true;
    } else if (t < 420) {
        int i = t - 405;
        w = feat[b * 492 + (i / 3) * 84 + 81 + (i % 3)];
        valid = true;
    }
    if (valid) {
        _Float16 h = (_Float16)w;
        h2 hh = { h, h };
        wtab[b * 448 + t] = H2U(hh);
    }
}

// ---------------- main fused kernel ----------------
__global__ __launch_bounds__(512, 8) void fused_net(
    const float* __restrict__ xin,
    const float* __restrict__ thumb,
    const float* __restrict__ feat,
    const uint*  __restrict__ wtab,
    float* __restrict__ out)
{
    const int tid = threadIdx.x;

    // ---- thumb passthrough blocks (whole block exits before any barrier) ----
    if (blockIdx.x == 16) {
        const int part = blockIdx.y + 32 * blockIdx.z;     // 0..255
        const float4* s4 = (const float4*)thumb;
        float4* d4 = (float4*)(out + 25165824ull);
        const int n4 = 1572864 / 4;
        for (int i = part * 512 + tid; i < n4; i += 256 * 512)
            d4[i] = s4[i];
        return;
    }

    const int gx0 = blockIdx.x * 64;
    const int gy0 = blockIdx.y * 32;
    const int b   = blockIdx.z;
    const bool edge = (gx0 == 0) | (gx0 == 960) | (gy0 == 0) | (gy0 == 992);
    const float* wf = feat + b * 492;        // uniform fp32 (epilogue)
    const uint*  wt = wtab + b * 448;        // uniform packed half2 (conv)

    __shared__ __align__(16) uint lds[2 * BUF_U + 8];   // 40352 B
    uint* b0 = lds;
    uint* b1 = lds + BUF_U + 4;              // dword offset 5044 -> 16B aligned

    // ---- stage: f32 global -> half2 LDS. dword u <-> gx = gx0-6+2u (even) ----
    // incremental (ch,row,u) walk: idx = tid + 512*it, 512 = 13*38 + 18
    const float* xb = xin + ((size_t)(b * 3) << 20);
    {
        int srow = tid / 38;
        int su   = tid - srow * 38;          // tid<512 -> srow<=13, ch=0
        int sch  = 0;
        if (!edge) {
            #pragma unroll
            for (int it = 0; it < 10; ++it) {
                if (it < 9 || tid < 180) {
                    const float2 f = *(const float2*)(xb + ((size_t)sch << 20) +
                                                      ((size_t)(gy0 - 5 + srow) << 10) +
                                                      (gx0 - 6 + 2 * su));
                    b0[sch * CHP_U + srow * W_U + su] =
                        __builtin_bit_cast(uint, __builtin_amdgcn_cvt_pkrtz(f.x, f.y));
                }
                su += 18; srow += 13;
                if (su >= 38)   { su -= 38; srow += 1; }
                if (srow >= 42) { srow -= 42; sch += 1; }
            }
        } else {
            #pragma unroll
            for (int it = 0; it < 10; ++it) {
                if (it < 9 || tid < 180) {
                    const int gy = gy0 - 5 + srow;
                    const int gx = gx0 - 6 + 2 * su;   // even; gx<1024 => gx+1<=1023
                    float2 f = {0.f, 0.f};
                    if ((unsigned)gy < 1024u && (unsigned)gx < 1024u)
                        f = *(const float2*)(xb + ((size_t)sch << 20) +
                                             ((size_t)gy << 10) + gx);
                    b0[sch * CHP_U + srow * W_U + su] =
                        __builtin_bit_cast(uint, __builtin_amdgcn_cvt_pkrtz(f.x, f.y));
                }
                su += 18; srow += 13;
                if (su >= 38)   { su -= 38; srow += 1; }
                if (srow >= 42) { srow -= 42; sch += 1; }
            }
        }
    }
    __syncthreads();

    // ---- epilogue coords + pre-read residual (b0 is clobbered at l=1) ----
    const int er  = tid >> 5;                // 0..15
    const int uc  = tid & 31;                // out dword 3+uc (px 6..69)
    const int ub0 = (5 + er) * W_U + 3 + uc;
    const int ub1 = ub0 + 16 * W_U;
    uint resu[2][3];
    #pragma unroll
    for (int ch = 0; ch < 3; ++ch) {
        resu[0][ch] = b0[ch * CHP_U + ub0];
        resu[1][ch] = b0[ch * CHP_U + ub1];
    }

    // ---- conv thread coords (uniform across layers) + hoisted border masks ----
    const int cr = tid / 18;                 // 0..19  (valid when tid<360)
    const int cc = tid - cr * 18;            // 0..17
    const int y0 = 1 + 2 * cr;               // rows y0,y0+1 in 1..40
    const int x0 = 2 + 4 * cc;               // local px x0..x0+3 in 2..73
    uint mA[2] = {~0u, ~0u}, mB[2] = {~0u, ~0u};
    if (edge) {
        const int gyA = gy0 - 5 + y0;
        const int gxA = gx0 - 6 + x0;
        const uint mA0 = ((((unsigned)gxA       < 1024u) ? 0x0000ffffu : 0u) |
                          (((unsigned)(gxA + 1) < 1024u) ? 0xffff0000u : 0u));
        const uint mB0 = ((((unsigned)(gxA + 2) < 1024u) ? 0x0000ffffu : 0u) |
                          (((unsigned)(gxA + 3) < 1024u) ? 0xffff0000u : 0u));
        #pragma unroll
        for (int j = 0; j < 2; ++j) {
            const uint mr = ((unsigned)(gyA + j) < 1024u) ? ~0u : 0u;
            mA[j] = mA0 & mr;
            mB[j] = mB0 & mr;
        }
    }

    const h2 c02 = { (_Float16)0.2f, (_Float16)0.2f };

    // ---- 5 conv3x3 residual+leaky layers, packed fp16, ping-pong ----
    // Thread = 4px x 2 rows; input rows streamed (row t feeds out row j via
    // ky=t-j); center residual folded at t=1/t=2. All LDS addrs base+imm.
    #pragma unroll
    for (int l = 0; l < 5; ++l) {
        const uint* sb = (l & 1) ? b1 : b0;
        uint*       db = (l & 1) ? b0 : b1;
        if (tid < 360) {
            const uint* tb = sb + (y0 - 1) * W_U + 2 * cc;   // even dword -> 8B reads
            uint*       ob = db + y0 * W_U + 1 + 2 * cc;
            h2 accA[2][3], accB[2][3];
            #pragma unroll
            for (int oc = 0; oc < 3; ++oc) {
                const h2 bi = U2H(wt[405 + l * 3 + oc]);
                accA[0][oc] = bi; accA[1][oc] = bi;
                accB[0][oc] = bi; accB[1][oc] = bi;
            }
            #pragma unroll
            for (int ic = 0; ic < 3; ++ic) {
                #pragma unroll
                for (int t = 0; t < 4; ++t) {
                    const uint2 P = *(const uint2*)(tb + ic * CHP_U + t * W_U);
                    const uint2 Q = *(const uint2*)(tb + ic * CHP_U + t * W_U + 2);
                    const uint u0 = P.x, u1 = P.y, u2 = Q.x, u3 = Q.y;
                    const h2 X01 = U2H((u0 >> 16) | (u1 << 16));   // halves {1,2}
                    const h2 C1  = U2H(u1);
                    const h2 X12 = U2H((u1 >> 16) | (u2 << 16));   // halves {3,4}
                    const h2 C2  = U2H(u2);
                    const h2 X23 = U2H((u2 >> 16) | (u3 << 16));   // halves {5,6}
                    #pragma unroll
                    for (int j = 0; j < 2; ++j) {
                        const int ky = t - j;
                        if (0 <= ky && ky <= 2) {
                            const int wb = l * 81 + (ic * 3 + ky) * 9;
                            #pragma unroll
                            for (int oc = 0; oc < 3; ++oc) {
                                const h2 w0 = U2H(wt[wb + oc * 3 + 0]);
                                const h2 w1 = U2H(wt[wb + oc * 3 + 1]);
                                const h2 w2 = U2H(wt[wb + oc * 3 + 2]);
                                accA[j][oc] = __builtin_elementwise_fma(w0, X01, accA[j][oc]);
                                accA[j][oc] = __builtin_elementwise_fma(w1, C1,  accA[j][oc]);
                                accA[j][oc] = __builtin_elementwise_fma(w2, X12, accA[j][oc]);
                                accB[j][oc] = __builtin_elementwise_fma(w0, X12, accB[j][oc]);
                                accB[j][oc] = __builtin_elementwise_fma(w1, C2,  accB[j][oc]);
                                accB[j][oc] = __builtin_elementwise_fma(w2, X23, accB[j][oc]);
                            }
                        }
                    }
                    if (t == 1) { accA[0][ic] = accA[0][ic] + C1; accB[0][ic] = accB[0][ic] + C2; }
                    if (t == 2) { accA[1][ic] = accA[1][ic] + C1; accB[1][ic] = accB[1][ic] + C2; }
                }
            }
            // leaky 0.2 = max(v, 0.2*v); interior blocks store unmasked
            if (!edge) {
                #pragma unroll
                for (int j = 0; j < 2; ++j) {
                    #pragma unroll
                    for (int oc = 0; oc < 3; ++oc) {
                        h2 vA = accA[j][oc]; vA = __builtin_elementwise_max(vA, c02 * vA);
                        h2 vB = accB[j][oc]; vB = __builtin_elementwise_max(vB, c02 * vB);
                        ob[oc * CHP_U + j * W_U]     = H2U(vA);
                        ob[oc * CHP_U + j * W_U + 1] = H2U(vB);
                    }
                }
            } else {
                #pragma unroll
                for (int j = 0; j < 2; ++j) {
                    #pragma unroll
                    for (int oc = 0; oc < 3; ++oc) {
                        h2 vA = accA[j][oc]; vA = __builtin_elementwise_max(vA, c02 * vA);
                        h2 vB = accB[j][oc]; vB = __builtin_elementwise_max(vB, c02 * vB);
                        ob[oc * CHP_U + j * W_U]     = H2U(vA) & mA[j];
                        ob[oc * CHP_U + j * W_U + 1] = H2U(vB) & mB[j];
                    }
                }
            }
        }
        __syncthreads();
    }
    // final conv3 result is in b1

    // ---- epilogue: conv1x1 + global residual + attention (fp32), 2 rows ----
    float* outb = out + ((size_t)(b * 3) << 20);
    #pragma unroll
    for (int rr = 0; rr < 2; ++rr) {
        const int ub = rr ? ub1 : ub0;
        const int gy = gy0 + er + 16 * rr;
        float x5f[3][2], resf[3][2];
        #pragma unroll
        for (int ch = 0; ch < 3; ++ch) {
            h2 hr = U2H(resu[rr][ch]);
            resf[ch][0] = (float)hr.x; resf[ch][1] = (float)hr.y;
            h2 hx = U2H(b1[ch * CHP_U + ub]);
            x5f[ch][0] = (float)hx.x; x5f[ch][1] = (float)hx.y;
        }
        const float h1 = (float)gy * (1.0f / 1024.0f);
        const float h2v = h1 * h1, h3 = h2v * h1;
        float tmp[3][2];
        #pragma unroll
        for (int j = 0; j < 2; ++j) {
            const float wc = (float)(gx0 + 2 * uc + j) * (1.0f / 1024.0f);
            const float w2 = wc * wc, w3 = w2 * wc;
            const float hw = h1 * wc, h2w = h2v * wc, hw2 = h1 * w2;
            #pragma unroll
            for (int oc = 0; oc < 3; ++oc) {
                float s = x5f[oc][j] + wf[429 + oc]
                        + wf[420 + oc * 3 + 0] * x5f[0][j]
                        + wf[420 + oc * 3 + 1] * x5f[1][j]
                        + wf[420 + oc * 3 + 2] * x5f[2][j];
                s = s >= 0.f ? s : 0.2f * s;
                const float xf = resf[oc][j] + s;
                const float x1 = xf, x2 = x1 * x1, x3 = x2 * x1;
                const float* cf = wf + 432 + oc * 20;
                float att =
                    cf[0] * h3 + cf[1] * h2w + cf[2] * h2v * x1 + cf[3] * h2v +
                    cf[4] * hw2 + cf[5] * hw * x1 + cf[6] * hw + cf[7] * h1 * x2 +
                    cf[8] * h1 * x1 + cf[9] * h1 + cf[10] * w3 + cf[11] * w2 * x1 +
                    cf[12] * w2 + cf[13] * wc * x2 + cf[14] * wc * x1 + cf[15] * wc +
                    cf[16] * x3 + cf[17] * x2 + cf[18] * x1 + cf[19];
                tmp[oc][j] = xf * (1.f + att);
            }
        }
        #pragma unroll
        for (int oc = 0; oc < 3; ++oc) {
            float2 v = {tmp[oc][0], tmp[oc][1]};
            *(float2*)&outb[((size_t)oc << 20) + ((size_t)gy << 10) + (gx0 + 2 * uc)] = v;
        }
    }
}

extern "C" void kernel_launch(void* const* d_in, const int* in_sizes, int n_in,
                              void* d_out, int out_size, void* d_ws, size_t ws_size,
                              hipStream_t stream) {
    const float* x     = (const float*)d_in[0];
    const float* thumb = (const float*)d_in[1];
    const float* feat  = (const float*)d_in[2];
    float* out = (float*)d_out;
    uint* wtab = (uint*)d_ws;   // 8 * 448 dwords = 14336 B

    prep_weights<<<dim3(8), 448, 0, stream>>>(feat, wtab);
    dim3 grid(17, 32, 8);       // x==16 blocks do the thumb copy
    fused_net<<<grid, 512, 0, stream>>>(x, thumb, feat, wtab, out);
}